// Round 2
// baseline (12.114 us; speedup 1.0000x reference)
//
#include <hip/hip_runtime.h>

#define NF 64
#define RANK 16
// 16 lanes per output, 2 outputs per group, 16 groups per 256-thread block.

__global__ __launch_bounds__(256) void MF_27436251087258_kernel(
    const int* __restrict__ users,
    const int* __restrict__ items,
    const float* __restrict__ user_emb,
    const float* __restrict__ item_emb,
    const float* __restrict__ user_bias,
    const float* __restrict__ item_bias,
    const float* __restrict__ A,
    const float* __restrict__ Bm,
    float* __restrict__ out,
    int batch)
{
    __shared__ float Bs[RANK * NF];   // 4 KB

    const int tid   = threadIdx.x;
    const int group = tid >> 4;
    const int lane  = tid & 15;
    const int base  = (blockIdx.x * 16 + group) * 2;   // first of 2 outputs

    // ---- 1. Index loads first (start the dependent chain immediately).
    const int2 uu = *(const int2*)(users + base);      // u0, u1
    const int2 ii = *(const int2*)(items + base);      // it0, it1

    // ---- 2. Independent B-staging load overlaps the idx round trip.
    const float4 bstage = ((const float4*)Bm)[tid];    // 256 x 16B = 4 KB

    // ---- 3. Gathers + bias loads, all issued as soon as indices arrive.
    const float4 ue0 = *(const float4*)(user_emb + (size_t)uu.x * NF + lane * 4);
    const float4 ie0 = *(const float4*)(item_emb + (size_t)ii.x * NF + lane * 4);
    const float4 ue1 = *(const float4*)(user_emb + (size_t)uu.y * NF + lane * 4);
    const float4 ie1 = *(const float4*)(item_emb + (size_t)ii.y * NF + lane * 4);
    const float  a0  = A[(size_t)ii.x * RANK + lane];
    const float  a1  = A[(size_t)ii.y * RANK + lane];
    const float  ub0 = user_bias[uu.x];
    const float  ib0 = item_bias[ii.x];
    const float  ub1 = user_bias[uu.y];
    const float  ib1 = item_bias[ii.y];

    // ---- 4. Stage B into LDS (waits only on bstage), then barrier.
    ((float4*)Bs)[tid] = bstage;
    __syncthreads();

    // ---- 5. Low-rank correction for both outputs, sharing each B read.
    float c00 = 0.f, c01 = 0.f, c02 = 0.f, c03 = 0.f;
    float c10 = 0.f, c11 = 0.f, c12 = 0.f, c13 = 0.f;
    #pragma unroll
    for (int r = 0; r < RANK; ++r) {
        const float  ar0 = __shfl(a0, r, 16);
        const float  ar1 = __shfl(a1, r, 16);
        const float4 br  = ((const float4*)(Bs + r * NF))[lane];
        c00 = fmaf(ar0, br.x, c00);  c10 = fmaf(ar1, br.x, c10);
        c01 = fmaf(ar0, br.y, c01);  c11 = fmaf(ar1, br.y, c11);
        c02 = fmaf(ar0, br.z, c02);  c12 = fmaf(ar1, br.z, c12);
        c03 = fmaf(ar0, br.w, c03);  c13 = fmaf(ar1, br.w, c13);
    }

    // ---- 6. Partial dots.
    float p0 = ue0.x * (ie0.x + c00)
             + ue0.y * (ie0.y + c01)
             + ue0.z * (ie0.z + c02)
             + ue0.w * (ie0.w + c03);
    float p1 = ue1.x * (ie1.x + c10)
             + ue1.y * (ie1.y + c11)
             + ue1.z * (ie1.z + c12)
             + ue1.w * (ie1.w + c13);

    // ---- 7. Reduce across the 16-lane group.
    p0 += __shfl_xor(p0, 8, 16);  p1 += __shfl_xor(p1, 8, 16);
    p0 += __shfl_xor(p0, 4, 16);  p1 += __shfl_xor(p1, 4, 16);
    p0 += __shfl_xor(p0, 2, 16);  p1 += __shfl_xor(p1, 2, 16);
    p0 += __shfl_xor(p0, 1, 16);  p1 += __shfl_xor(p1, 1, 16);

    if (lane == 0 && base + 1 < batch) {
        out[base]     = p0 + ub0 + ib0;
        out[base + 1] = p1 + ub1 + ib1;
    }
}

extern "C" void kernel_launch(void* const* d_in, const int* in_sizes, int n_in,
                              void* d_out, int out_size, void* d_ws, size_t ws_size,
                              hipStream_t stream) {
    const int*   users     = (const int*)  d_in[0];
    const int*   items     = (const int*)  d_in[1];
    const float* user_emb  = (const float*)d_in[2];
    const float* item_emb  = (const float*)d_in[3];
    const float* user_bias = (const float*)d_in[4];
    const float* item_bias = (const float*)d_in[5];
    const float* A         = (const float*)d_in[6];
    const float* Bm        = (const float*)d_in[7];
    float* out = (float*)d_out;

    const int batch = in_sizes[0];                 // 16384
    const int outputs_per_block = 32;              // 16 groups x 2 outputs
    const int grid = (batch + outputs_per_block - 1) / outputs_per_block;  // 512

    MF_27436251087258_kernel<<<grid, 256, 0, stream>>>(
        users, items, user_emb, item_emb, user_bias, item_bias, A, Bm, out, batch);
}

// Round 3
// 10.823 us; speedup vs baseline: 1.1193x; 1.1193x over previous
//
#include <hip/hip_runtime.h>

#define NF 64
#define RANK 16
// 16 lanes per output, 16 groups per 256-thread block, 1024 blocks.
// No LDS, no barrier: B (4 KB) is L1-resident after first touch; A row is one
// broadcast cache line; all random lines per output issued back-to-back.

__global__ __launch_bounds__(256) void MF_27436251087258_kernel(
    const int* __restrict__ users,
    const int* __restrict__ items,
    const float* __restrict__ user_emb,
    const float* __restrict__ item_emb,
    const float* __restrict__ user_bias,
    const float* __restrict__ item_bias,
    const float* __restrict__ A,
    const float* __restrict__ Bm,
    float* __restrict__ out,
    int batch)
{
    const int tid   = threadIdx.x;
    const int group = tid >> 4;
    const int lane  = tid & 15;
    const int i = blockIdx.x * 16 + group;
    if (i >= batch) return;

    // ---- 1. Indices (broadcast within group).
    const int u  = users[i];
    const int it = items[i];

    // ---- 2. All random-line loads issued immediately: biases, rows, A-row.
    const float ub = user_bias[u];
    const float ib = item_bias[it];

    const float4 ue = *(const float4*)(user_emb + (size_t)u  * NF + lane * 4);
    const float4 ie = *(const float4*)(item_emb + (size_t)it * NF + lane * 4);

    const float* Arow = A + (size_t)it * RANK;      // 64 B, one cache line
    const float4 a0 = *(const float4*)(Arow + 0);
    const float4 a1 = *(const float4*)(Arow + 4);
    const float4 a2 = *(const float4*)(Arow + 8);
    const float4 a3 = *(const float4*)(Arow + 12);
    const float ar[RANK] = { a0.x, a0.y, a0.z, a0.w,
                             a1.x, a1.y, a1.z, a1.w,
                             a2.x, a2.y, a2.z, a2.w,
                             a3.x, a3.y, a3.z, a3.w };

    // ---- 3. Low-rank correction. Each loop iter is one fully-coalesced
    // 256 B read of B row r per wave (L1-resident after first touch).
    float c0 = 0.f, c1 = 0.f, c2 = 0.f, c3 = 0.f;
    #pragma unroll
    for (int r = 0; r < RANK; ++r) {
        const float4 br = *(const float4*)(Bm + r * NF + lane * 4);
        c0 = fmaf(ar[r], br.x, c0);
        c1 = fmaf(ar[r], br.y, c1);
        c2 = fmaf(ar[r], br.z, c2);
        c3 = fmaf(ar[r], br.w, c3);
    }

    // ---- 4. Partial dot: ue . (ie + corr)
    float p = ue.x * (ie.x + c0)
            + ue.y * (ie.y + c1)
            + ue.z * (ie.z + c2)
            + ue.w * (ie.w + c3);

    // ---- 5. Reduce across the 16-lane group.
    p += __shfl_xor(p, 8, 16);
    p += __shfl_xor(p, 4, 16);
    p += __shfl_xor(p, 2, 16);
    p += __shfl_xor(p, 1, 16);

    if (lane == 0) {
        out[i] = p + ub + ib;
    }
}

extern "C" void kernel_launch(void* const* d_in, const int* in_sizes, int n_in,
                              void* d_out, int out_size, void* d_ws, size_t ws_size,
                              hipStream_t stream) {
    const int*   users     = (const int*)  d_in[0];
    const int*   items     = (const int*)  d_in[1];
    const float* user_emb  = (const float*)d_in[2];
    const float* item_emb  = (const float*)d_in[3];
    const float* user_bias = (const float*)d_in[4];
    const float* item_bias = (const float*)d_in[5];
    const float* A         = (const float*)d_in[6];
    const float* Bm        = (const float*)d_in[7];
    float* out = (float*)d_out;

    const int batch = in_sizes[0];             // 16384
    const int groups_per_block = 16;           // 256 threads / 16 lanes
    const int grid = (batch + groups_per_block - 1) / groups_per_block;  // 1024

    MF_27436251087258_kernel<<<grid, 256, 0, stream>>>(
        users, items, user_emb, item_emb, user_bias, item_bias, A, Bm, out, batch);
}